// Round 10
// baseline (47.566 us; speedup 1.0000x reference)
//
#include <hip/hip_runtime.h>

typedef __bf16 bf16x8 __attribute__((ext_vector_type(8)));
typedef float  f32x4  __attribute__((ext_vector_type(4)));

#define KDIM    784
#define KSTEP   32
#define NSTEPS  25          // ceil(784/32) -> K padded to 800
#define NCOLS   128
#define NT      8           // 128 / 16 col-tiles
#define WAVES   4
#define ROWS_PER_WAVE 32
#define ROWS_PER_BLOCK (WAVES * ROWS_PER_WAVE)   // 128
#define XSTEP_BYTES 16384   // one k-step of x: 128 rows x 128 B
#define WSTEP_BYTES 8192    // one k-step of B-frags: 8 frags * 64 lanes * 16 B
#define NBUF 3              // triple buffer: 2 stages always in flight
#define HSH_PAD 132
#define HCHUNK  16          // fc2 processes 16 rows per m-chunk
// LDS: [0,48K) x tri-buf, [48K,72K) wfrag tri-buf; hsh (33 KB) aliases from 0.

// ---------------------------------------------------------------------------
// Prep: Weff[j,k] = sum_{u,v} conv_w[u,v] * fc1_w[j,(r-u)*26+(c-v)], stored as
// bf16 MFMA B-fragments: wfrag[((s*NT + n)*64 + lane)*8 + j] holds
// Weff[col = n*16 + (lane&15)][k = s*32 + (lane>>4)*8 + j]   (0 if k >= 784).
// 200 blocks x 64 threads (R8 win: spreads latency-bound reads over 200 CUs).
// ---------------------------------------------------------------------------
__global__ __launch_bounds__(64) void prep_weff(
    const float* __restrict__ conv_w,
    const float* __restrict__ fc1_w,
    __bf16* __restrict__ wfrag)
{
  int idx = blockIdx.x * 64 + threadIdx.x;      // 200*64 = 12800 exactly
  if (idx >= NSTEPS * NT * 64) return;
  int lane = idx & 63;
  int n    = (idx >> 6) & (NT - 1);
  int s    = idx >> 9;
  int col  = n * 16 + (lane & 15);
  int kb   = s * KSTEP + (lane >> 4) * 8;
  bf16x8 o;
#pragma unroll
  for (int j = 0; j < 8; ++j) {
    int k = kb + j;
    float v = 0.f;
    if (k < KDIM) {
      int r = k / 28, c = k % 28;
#pragma unroll
      for (int u = 0; u < 3; ++u)
#pragma unroll
        for (int w = 0; w < 3; ++w) {
          int p = r - u, q = c - w;
          if (p >= 0 && p < 26 && q >= 0 && q < 26)
            v = fmaf(conv_w[u * 3 + w], fc1_w[col * 676 + p * 26 + q], v);
        }
    }
    o[j] = (__bf16)v;
  }
  reinterpret_cast<bf16x8*>(wfrag)[idx] = o;
}

__device__ __forceinline__ bf16x8 pack8(f32x4 lo, f32x4 hi) {
  bf16x8 r;
  r[0] = (__bf16)lo[0]; r[1] = (__bf16)lo[1];
  r[2] = (__bf16)lo[2]; r[3] = (__bf16)lo[3];
  r[4] = (__bf16)hi[0]; r[5] = (__bf16)hi[1];
  r[6] = (__bf16)hi[2]; r[7] = (__bf16)hi[3];
  return r;
}

// Split 8 fp32 into bf16 hi + bf16 residual lo (hi+lo reproduces fp32 to ~2^-17)
__device__ __forceinline__ void split8(f32x4 a, f32x4 b, bf16x8& hi, bf16x8& lo) {
#pragma unroll
  for (int j = 0; j < 4; ++j) {
    __bf16 h = (__bf16)a[j]; hi[j] = h; lo[j] = (__bf16)(a[j] - (float)h);
  }
#pragma unroll
  for (int j = 0; j < 4; ++j) {
    __bf16 h = (__bf16)b[j]; hi[4 + j] = h; lo[4 + j] = (__bf16)(b[j] - (float)h);
  }
}

// Copy one k-step of x (dense lines, pre-swizzled source) + wfrag into LDS.
// Exactly 6 global_load_lds per wave (4 x-chunks + 2 wfrag chunks) -> the
// counted vmcnt in the K loop is 6 per stage in flight.
__device__ __forceinline__ void stage_copy(
    const float* __restrict__ xrowbase, const __bf16* __restrict__ wfrag,
    unsigned char* smem, int buf, int t, int wave, int lane)
{
  unsigned char* xdst = smem + buf * XSTEP_BYTES;
  int sb = ((lane & 7) * 16) ^ (((lane >> 3) & 7) << 4);   // swizzled byte-in-chunk
  int row_off = t * 128 + sb;
  if (row_off + 16 > KDIM * 4) row_off = 0;   // tail clamp; wfrag zeros kill k>=784
#pragma unroll
  for (int i = 0; i < 4; ++i) {
    int c = wave * 4 + i;                     // chunk = rows [c*8, c*8+8)
    const unsigned char* src =
        (const unsigned char*)(xrowbase + (size_t)(c * 8 + (lane >> 3)) * KDIM) + row_off;
    unsigned char* dst = xdst + c * 1024 + lane * 16;
    __builtin_amdgcn_global_load_lds(
        (const __attribute__((address_space(1))) unsigned int*)src,
        (__attribute__((address_space(3))) unsigned int*)dst, 16, 0, 0);
  }
  unsigned char* wdst = smem + NBUF * XSTEP_BYTES + buf * WSTEP_BYTES;
  const unsigned char* wsrc = (const unsigned char*)wfrag + (size_t)t * WSTEP_BYTES;
#pragma unroll
  for (int i = 0; i < 2; ++i) {
    int c = wave * 2 + i;
    const unsigned char* src = wsrc + c * 1024 + lane * 16;
    unsigned char* dst = wdst + c * 1024 + lane * 16;
    __builtin_amdgcn_global_load_lds(
        (const __attribute__((address_space(1))) unsigned int*)src,
        (__attribute__((address_space(3))) unsigned int*)dst, 16, 0, 0);
  }
}

// ---------------------------------------------------------------------------
// Main: per block 4 waves x 32 rows = 128 rows, all 128 h-columns via MFMA.
// x + B-frags staged via dense-line global_load_lds, TRIPLE-buffered with
// counted vmcnt(6) barriers (T3/T4): the next-next stage's 6 loads stay in
// flight ACROSS each barrier; only the next stage's 6 are drained. Loads get
// ~2 stages (~800 cy) to cover HBM latency and the VMEM queue never empties.
// fc2 (128->10) via hi/lo-split bf16 MFMA in two 16-row chunks.
// ---------------------------------------------------------------------------
__global__ __launch_bounds__(256, 2) void fused_mlp(
    const float*  __restrict__ x,
    const __bf16* __restrict__ wfrag,
    const float*  __restrict__ fc1_b,
    const float*  __restrict__ fc2_w,
    const float*  __restrict__ fc2_b,
    float*        __restrict__ out)
{
  __shared__ __align__(16) unsigned char smem[NBUF * XSTEP_BYTES + NBUF * WSTEP_BYTES];
  float (*hsh)[HCHUNK][HSH_PAD] =
      reinterpret_cast<float (*)[HCHUNK][HSH_PAD]>(smem);   // 33 KB alias

  int tid  = threadIdx.x;
  int wave = tid >> 6, lane = tid & 63;
  int lrow = lane & 15;      // A row within 16-tile / B col within 16-tile
  int lgrp = lane >> 4;      // k sub-group
  long wrow0 = (long)blockIdx.x * ROWS_PER_BLOCK + wave * ROWS_PER_WAVE;
  const float* xrowbase = x + (long)blockIdx.x * ROWS_PER_BLOCK * KDIM;

  f32x4 acc[2][NT];
#pragma unroll
  for (int m = 0; m < 2; ++m)
#pragma unroll
    for (int n = 0; n < NT; ++n) acc[m][n] = (f32x4){0.f, 0.f, 0.f, 0.f};

  // fragment LDS addresses (constant across stages except buffer base)
  int base0 = (wave * 32 + lrow) * 128;
  int base1 = base0 + 16 * 128;
  int swz   = (lrow & 7) << 4;
  int sb0   = (lgrp * 32) ^ swz;
  int sb1   = (lgrp * 32 + 16) ^ swz;

// compute one k-step from buffer BUF
#define STEP_COMPUTE(BUF)                                                      \
  {                                                                            \
    const unsigned char* xb = smem + (BUF) * XSTEP_BYTES;                      \
    const bf16x8* bp =                                                         \
        (const bf16x8*)(smem + NBUF * XSTEP_BYTES + (BUF) * WSTEP_BYTES) + lane; \
    f32x4 x00 = *(const f32x4*)(xb + base0 + sb0);                             \
    f32x4 x01 = *(const f32x4*)(xb + base0 + sb1);                             \
    f32x4 x10 = *(const f32x4*)(xb + base1 + sb0);                             \
    f32x4 x11 = *(const f32x4*)(xb + base1 + sb1);                             \
    bf16x8 a0 = pack8(x00, x01);                                               \
    bf16x8 a1 = pack8(x10, x11);                                               \
    bf16x8 bf[NT];                                                             \
    _Pragma("unroll")                                                          \
    for (int n = 0; n < NT; ++n) bf[n] = bp[n * 64];                           \
    _Pragma("unroll")                                                          \
    for (int n = 0; n < NT; ++n) {                                             \
      acc[0][n] = __builtin_amdgcn_mfma_f32_16x16x32_bf16(a0, bf[n], acc[0][n], 0, 0, 0); \
      acc[1][n] = __builtin_amdgcn_mfma_f32_16x16x32_bf16(a1, bf[n], acc[1][n], 0, 0, 0); \
    }                                                                          \
  }

  // ---- prologue: issue S_0, S_1; drain S_0 only ---------------------------
  stage_copy(xrowbase, wfrag, smem, 0, 0, wave, lane);   // S_0: 6 vmem
  stage_copy(xrowbase, wfrag, smem, 1, 1, wave, lane);   // S_1: 6 vmem
  __builtin_amdgcn_sched_barrier(0);                     // keep issues above wait
  asm volatile("s_waitcnt vmcnt(6)" ::: "memory");       // S_0 landed; S_1 in flight
  __builtin_amdgcn_s_barrier();                          // buf0 ready for all waves

  // ---- steady K loop: t = 0..22 (S_{t+2} always exists) -------------------
  int cur = 0;
  for (int t = 0; t < NSTEPS - 2; ++t) {
    int iss = cur + 2; if (iss >= NBUF) iss -= NBUF;
    stage_copy(xrowbase, wfrag, smem, iss, t + 2, wave, lane);  // S_{t+2}: +6
    STEP_COMPUTE(cur);
    __builtin_amdgcn_sched_barrier(0);                   // keep issues above wait
    asm volatile("s_waitcnt vmcnt(6)" ::: "memory");     // S_{t+1} landed; S_{t+2} stays
    __builtin_amdgcn_s_barrier();                        // buf[t+1] ready for all
    ++cur; if (cur >= NBUF) cur -= NBUF;
  }

  // ---- t = 23: nothing to issue; drain S_24 fully -------------------------
  STEP_COMPUTE(cur);
  asm volatile("s_waitcnt vmcnt(0)" ::: "memory");       // S_24 landed
  __builtin_amdgcn_s_barrier();
  ++cur; if (cur >= NBUF) cur -= NBUF;

  // ---- t = 24: last k-step -------------------------------------------------
  STEP_COMPUTE(cur);
  __syncthreads();   // all staging reads done before hsh overwrites the buffers

  // ---- fc2 B-fragments from fc2_w (L2-resident), hi/lo split --------------
  // B-frag: col(lane&15)=o, k=(lane>>4)*8+j
  int osafe = (lrow < 10) ? lrow : 9;
  bf16x8 whi[4], wlo[4];
#pragma unroll
  for (int s2 = 0; s2 < 4; ++s2) {
    f32x4 w0 = *(const f32x4*)(fc2_w + osafe * NCOLS + s2 * 32 + lgrp * 8);
    f32x4 w1 = *(const f32x4*)(fc2_w + osafe * NCOLS + s2 * 32 + lgrp * 8 + 4);
    if (lrow >= 10) { w0 = (f32x4){0.f,0.f,0.f,0.f}; w1 = (f32x4){0.f,0.f,0.f,0.f}; }
    split8(w0, w1, whi[s2], wlo[s2]);
  }
  float b2 = (lrow < 10) ? fc2_b[lrow] : 0.f;
  float bcol[NT];
#pragma unroll
  for (int n = 0; n < NT; ++n) bcol[n] = fc1_b[n * 16 + lrow];

  // ---- epilogue in two 16-row chunks: bias+relu -> LDS -> fc2 MFMA --------
  // fc1 C/D layout (m89): col = lane&15, row = (lane>>4)*4 + reg_idx.
  // hsh[wave] is per-wave private: same-wave LDS RAW handled by lgkmcnt.
#pragma unroll
  for (int m2 = 0; m2 < 2; ++m2) {
#pragma unroll
    for (int n = 0; n < NT; ++n) {
      int col = n * 16 + lrow;
#pragma unroll
      for (int ri = 0; ri < 4; ++ri) {
        int rl = lgrp * 4 + ri;
        hsh[wave][rl][col] = fmaxf(acc[m2][n][ri] + bcol[n], 0.f);
      }
    }
    f32x4 acc2 = (f32x4){0.f, 0.f, 0.f, 0.f};
    const float* hr = &hsh[wave][lrow][0];
#pragma unroll
    for (int s2 = 0; s2 < 4; ++s2) {
      f32x4 h0 = *(const f32x4*)(hr + s2 * 32 + lgrp * 8);
      f32x4 h1 = *(const f32x4*)(hr + s2 * 32 + lgrp * 8 + 4);
      bf16x8 ahi, alo; split8(h0, h1, ahi, alo);
      acc2 = __builtin_amdgcn_mfma_f32_16x16x32_bf16(ahi, whi[s2], acc2, 0, 0, 0);
      acc2 = __builtin_amdgcn_mfma_f32_16x16x32_bf16(ahi, wlo[s2], acc2, 0, 0, 0);
      acc2 = __builtin_amdgcn_mfma_f32_16x16x32_bf16(alo, whi[s2], acc2, 0, 0, 0);
    }
    // D layout: col(lane&15)=o, row=(lane>>4)*4+reg -> rows m2*16+lgrp*4+ri
    if (lrow < 10) {
#pragma unroll
      for (int ri = 0; ri < 4; ++ri)
        out[(wrow0 + m2 * 16 + lgrp * 4 + ri) * 10 + lrow] = acc2[ri] + b2;
    }
  }
}

extern "C" void kernel_launch(void* const* d_in, const int* in_sizes, int n_in,
                              void* d_out, int out_size, void* d_ws, size_t ws_size,
                              hipStream_t stream) {
  const float* x      = (const float*)d_in[0];
  const float* conv_w = (const float*)d_in[1];
  const float* fc1_w  = (const float*)d_in[2];
  const float* fc1_b  = (const float*)d_in[3];
  const float* fc2_w  = (const float*)d_in[4];
  const float* fc2_b  = (const float*)d_in[5];
  float* outp = (float*)d_out;
  __bf16* wfrag = (__bf16*)d_ws;                // needs 25*8*64*8*2 B = 200 KiB

  int Btotal = in_sizes[0] / KDIM;              // 65536
  int prep_threads = NSTEPS * NT * 64;          // 12800

  hipLaunchKernelGGL(prep_weff, dim3(prep_threads / 64), dim3(64), 0, stream,
                     conv_w, fc1_w, wfrag);
  hipLaunchKernelGGL(fused_mlp, dim3(Btotal / ROWS_PER_BLOCK), dim3(256), 0, stream,
                     x, wfrag, fc1_b, fc2_w, fc2_b, outp);
}

// Round 11
// 47.046 us; speedup vs baseline: 1.0111x; 1.0111x over previous
//
#include <hip/hip_runtime.h>

typedef __bf16 bf16x8 __attribute__((ext_vector_type(8)));
typedef float  f32x4  __attribute__((ext_vector_type(4)));

#define KDIM    784
#define KSTEP   32
#define NSTEPS  25          // ceil(784/32) -> K padded to 800
#define NCOLS   128
#define NT      8           // 128 / 16 col-tiles
#define WAVES   4
#define ROWS_PER_WAVE 32
#define ROWS_PER_BLOCK (WAVES * ROWS_PER_WAVE)   // 128
#define XSTEP_BYTES 16384   // one k-step of x: 128 rows x 128 B
#define WSTEP_BYTES 8192    // one k-step of B-frags: 8 frags * 64 lanes * 16 B
#define HSH_PAD 132
#define HCHUNK  16          // fc2 processes 16 rows per m-chunk
// LDS: [0,32K) x dbuf, [32K,48K) wfrag dbuf; hsh (33 KB) aliases from 0.

// ---------------------------------------------------------------------------
// Prep: Weff[j,k] = sum_{u,v} conv_w[u,v] * fc1_w[j,(r-u)*26+(c-v)], stored as
// bf16 MFMA B-fragments: wfrag[((s*NT + n)*64 + lane)*8 + j] holds
// Weff[col = n*16 + (lane&15)][k = s*32 + (lane>>4)*8 + j]   (0 if k >= 784).
// 200 blocks x 64 threads (R8 win: spreads latency-bound reads over 200 CUs).
// ---------------------------------------------------------------------------
__global__ __launch_bounds__(64) void prep_weff(
    const float* __restrict__ conv_w,
    const float* __restrict__ fc1_w,
    __bf16* __restrict__ wfrag)
{
  int idx = blockIdx.x * 64 + threadIdx.x;      // 200*64 = 12800 exactly
  if (idx >= NSTEPS * NT * 64) return;
  int lane = idx & 63;
  int n    = (idx >> 6) & (NT - 1);
  int s    = idx >> 9;
  int col  = n * 16 + (lane & 15);
  int kb   = s * KSTEP + (lane >> 4) * 8;
  bf16x8 o;
#pragma unroll
  for (int j = 0; j < 8; ++j) {
    int k = kb + j;
    float v = 0.f;
    if (k < KDIM) {
      int r = k / 28, c = k % 28;
#pragma unroll
      for (int u = 0; u < 3; ++u)
#pragma unroll
        for (int w = 0; w < 3; ++w) {
          int p = r - u, q = c - w;
          if (p >= 0 && p < 26 && q >= 0 && q < 26)
            v = fmaf(conv_w[u * 3 + w], fc1_w[col * 676 + p * 26 + q], v);
        }
    }
    o[j] = (__bf16)v;
  }
  reinterpret_cast<bf16x8*>(wfrag)[idx] = o;
}

__device__ __forceinline__ bf16x8 pack8(f32x4 lo, f32x4 hi) {
  bf16x8 r;
  r[0] = (__bf16)lo[0]; r[1] = (__bf16)lo[1];
  r[2] = (__bf16)lo[2]; r[3] = (__bf16)lo[3];
  r[4] = (__bf16)hi[0]; r[5] = (__bf16)hi[1];
  r[6] = (__bf16)hi[2]; r[7] = (__bf16)hi[3];
  return r;
}

// Split 8 fp32 into bf16 hi + bf16 residual lo (hi+lo reproduces fp32 to ~2^-17)
__device__ __forceinline__ void split8(f32x4 a, f32x4 b, bf16x8& hi, bf16x8& lo) {
#pragma unroll
  for (int j = 0; j < 4; ++j) {
    __bf16 h = (__bf16)a[j]; hi[j] = h; lo[j] = (__bf16)(a[j] - (float)h);
  }
#pragma unroll
  for (int j = 0; j < 4; ++j) {
    __bf16 h = (__bf16)b[j]; hi[4 + j] = h; lo[4 + j] = (__bf16)(b[j] - (float)h);
  }
}

// Copy one k-step of x (dense lines, pre-swizzled source) + wfrag into LDS.
// x: 16 chunks of {8 rows x 128 B}; 8 consecutive lanes cover one row's 128 B
// chunk fully (16 dense 64B lines per instruction vs 32 half-used lines in the
// register path). Source byte pre-swizzled by ((row&7)<<4) so the linear LDS
// dest holds the XOR-swizzled layout (m173 pattern); frag ds_reads use the
// same XOR -> conflict-free.
__device__ __forceinline__ void stage_copy(
    const float* __restrict__ xrowbase, const __bf16* __restrict__ wfrag,
    unsigned char* smem, int buf, int t, int wave, int lane)
{
  unsigned char* xdst = smem + buf * XSTEP_BYTES;
  int sb = ((lane & 7) * 16) ^ (((lane >> 3) & 7) << 4);   // swizzled byte-in-chunk
  int row_off = t * 128 + sb;
  if (row_off + 16 > KDIM * 4) row_off = 0;   // tail clamp; wfrag zeros kill k>=784
#pragma unroll
  for (int i = 0; i < 4; ++i) {
    int c = wave * 4 + i;                     // chunk = rows [c*8, c*8+8)
    const unsigned char* src =
        (const unsigned char*)(xrowbase + (size_t)(c * 8 + (lane >> 3)) * KDIM) + row_off;
    unsigned char* dst = xdst + c * 1024 + lane * 16;
    __builtin_amdgcn_global_load_lds(
        (const __attribute__((address_space(1))) unsigned int*)src,
        (__attribute__((address_space(3))) unsigned int*)dst, 16, 0, 0);
  }
  unsigned char* wdst = smem + 2 * XSTEP_BYTES + buf * WSTEP_BYTES;
  const unsigned char* wsrc = (const unsigned char*)wfrag + (size_t)t * WSTEP_BYTES;
#pragma unroll
  for (int i = 0; i < 2; ++i) {
    int c = wave * 2 + i;
    const unsigned char* src = wsrc + c * 1024 + lane * 16;
    unsigned char* dst = wdst + c * 1024 + lane * 16;
    __builtin_amdgcn_global_load_lds(
        (const __attribute__((address_space(1))) unsigned int*)src,
        (__attribute__((address_space(3))) unsigned int*)dst, 16, 0, 0);
  }
}

// ---------------------------------------------------------------------------
// Main: per block 4 waves x 32 rows = 128 rows, all 128 h-columns via MFMA.
// BOTH x and B-frags staged via global_load_lds (dense-line requests),
// double-buffered, 25 single-k-step stages (barrier count proven irrelevant,
// R7/R10). A-fragments read from swizzled LDS (conflict-free). fc2 (128->10)
// via hi/lo-split bf16 MFMA in two 16-row chunks. MFMA order identical to
// prior rounds -> bit-identical accumulation.
// ---------------------------------------------------------------------------
__global__ __launch_bounds__(256, 2) void fused_mlp(
    const float*  __restrict__ x,
    const __bf16* __restrict__ wfrag,
    const float*  __restrict__ fc1_b,
    const float*  __restrict__ fc2_w,
    const float*  __restrict__ fc2_b,
    float*        __restrict__ out)
{
  __shared__ __align__(16) unsigned char smem[2 * XSTEP_BYTES + 2 * WSTEP_BYTES];
  float (*hsh)[HCHUNK][HSH_PAD] =
      reinterpret_cast<float (*)[HCHUNK][HSH_PAD]>(smem);   // 33 KB alias

  int tid  = threadIdx.x;
  int wave = tid >> 6, lane = tid & 63;
  int lrow = lane & 15;      // A row within 16-tile / B col within 16-tile
  int lgrp = lane >> 4;      // k sub-group
  long wrow0 = (long)blockIdx.x * ROWS_PER_BLOCK + wave * ROWS_PER_WAVE;
  const float* xrowbase = x + (long)blockIdx.x * ROWS_PER_BLOCK * KDIM;

  f32x4 acc[2][NT];
#pragma unroll
  for (int m = 0; m < 2; ++m)
#pragma unroll
    for (int n = 0; n < NT; ++n) acc[m][n] = (f32x4){0.f, 0.f, 0.f, 0.f};

  // fragment LDS addresses (constant across stages except buffer base)
  int base0 = (wave * 32 + lrow) * 128;
  int base1 = base0 + 16 * 128;
  int swz   = (lrow & 7) << 4;
  int sb0   = (lgrp * 32) ^ swz;
  int sb1   = (lgrp * 32 + 16) ^ swz;

  // ---- prologue: stage 0 ---------------------------------------------------
  stage_copy(xrowbase, wfrag, smem, 0, 0, wave, lane);

  // ---- K loop: 25 single-k-step stages ------------------------------------
  for (int t = 0; t < NSTEPS; ++t) {
    __syncthreads();   // stage(t) landed (vmcnt drain); stage(t-1) reads done
    if (t < NSTEPS - 1)
      stage_copy(xrowbase, wfrag, smem, (t + 1) & 1, t + 1, wave, lane);

    int buf = t & 1;
    const unsigned char* xb = smem + buf * XSTEP_BYTES;
    const bf16x8* bp =
        (const bf16x8*)(smem + 2 * XSTEP_BYTES + buf * WSTEP_BYTES) + lane;

    f32x4 x00 = *(const f32x4*)(xb + base0 + sb0);
    f32x4 x01 = *(const f32x4*)(xb + base0 + sb1);
    f32x4 x10 = *(const f32x4*)(xb + base1 + sb0);
    f32x4 x11 = *(const f32x4*)(xb + base1 + sb1);
    bf16x8 a0 = pack8(x00, x01);
    bf16x8 a1 = pack8(x10, x11);

    bf16x8 bf[NT];
#pragma unroll
    for (int n = 0; n < NT; ++n) bf[n] = bp[n * 64];
#pragma unroll
    for (int n = 0; n < NT; ++n) {
      acc[0][n] = __builtin_amdgcn_mfma_f32_16x16x32_bf16(a0, bf[n], acc[0][n], 0, 0, 0);
      acc[1][n] = __builtin_amdgcn_mfma_f32_16x16x32_bf16(a1, bf[n], acc[1][n], 0, 0, 0);
    }
  }
  __syncthreads();   // all staging reads done before hsh overwrites the buffers

  // ---- fc2 B-fragments from fc2_w (L2-resident), hi/lo split --------------
  // B-frag: col(lane&15)=o, k=(lane>>4)*8+j
  int osafe = (lrow < 10) ? lrow : 9;
  bf16x8 whi[4], wlo[4];
#pragma unroll
  for (int s2 = 0; s2 < 4; ++s2) {
    f32x4 w0 = *(const f32x4*)(fc2_w + osafe * NCOLS + s2 * 32 + lgrp * 8);
    f32x4 w1 = *(const f32x4*)(fc2_w + osafe * NCOLS + s2 * 32 + lgrp * 8 + 4);
    if (lrow >= 10) { w0 = (f32x4){0.f,0.f,0.f,0.f}; w1 = (f32x4){0.f,0.f,0.f,0.f}; }
    split8(w0, w1, whi[s2], wlo[s2]);
  }
  float b2 = (lrow < 10) ? fc2_b[lrow] : 0.f;
  float bcol[NT];
#pragma unroll
  for (int n = 0; n < NT; ++n) bcol[n] = fc1_b[n * 16 + lrow];

  // ---- epilogue in two 16-row chunks: bias+relu -> LDS -> fc2 MFMA --------
  // fc1 C/D layout (m89): col = lane&15, row = (lane>>4)*4 + reg_idx.
  // hsh[wave] is per-wave private: same-wave LDS RAW handled by lgkmcnt.
#pragma unroll
  for (int m2 = 0; m2 < 2; ++m2) {
#pragma unroll
    for (int n = 0; n < NT; ++n) {
      int col = n * 16 + lrow;
#pragma unroll
      for (int ri = 0; ri < 4; ++ri) {
        int rl = lgrp * 4 + ri;
        hsh[wave][rl][col] = fmaxf(acc[m2][n][ri] + bcol[n], 0.f);
      }
    }
    f32x4 acc2 = (f32x4){0.f, 0.f, 0.f, 0.f};
    const float* hr = &hsh[wave][lrow][0];
#pragma unroll
    for (int s2 = 0; s2 < 4; ++s2) {
      f32x4 h0 = *(const f32x4*)(hr + s2 * 32 + lgrp * 8);
      f32x4 h1 = *(const f32x4*)(hr + s2 * 32 + lgrp * 8 + 4);
      bf16x8 ahi, alo; split8(h0, h1, ahi, alo);
      acc2 = __builtin_amdgcn_mfma_f32_16x16x32_bf16(ahi, whi[s2], acc2, 0, 0, 0);
      acc2 = __builtin_amdgcn_mfma_f32_16x16x32_bf16(ahi, wlo[s2], acc2, 0, 0, 0);
      acc2 = __builtin_amdgcn_mfma_f32_16x16x32_bf16(alo, whi[s2], acc2, 0, 0, 0);
    }
    // D layout: col(lane&15)=o, row=(lane>>4)*4+reg -> rows m2*16+lgrp*4+ri
    if (lrow < 10) {
#pragma unroll
      for (int ri = 0; ri < 4; ++ri)
        out[(wrow0 + m2 * 16 + lgrp * 4 + ri) * 10 + lrow] = acc2[ri] + b2;
    }
  }
}

extern "C" void kernel_launch(void* const* d_in, const int* in_sizes, int n_in,
                              void* d_out, int out_size, void* d_ws, size_t ws_size,
                              hipStream_t stream) {
  const float* x      = (const float*)d_in[0];
  const float* conv_w = (const float*)d_in[1];
  const float* fc1_w  = (const float*)d_in[2];
  const float* fc1_b  = (const float*)d_in[3];
  const float* fc2_w  = (const float*)d_in[4];
  const float* fc2_b  = (const float*)d_in[5];
  float* outp = (float*)d_out;
  __bf16* wfrag = (__bf16*)d_ws;                // needs 25*8*64*8*2 B = 200 KiB

  int Btotal = in_sizes[0] / KDIM;              // 65536
  int prep_threads = NSTEPS * NT * 64;          // 12800

  hipLaunchKernelGGL(prep_weff, dim3(prep_threads / 64), dim3(64), 0, stream,
                     conv_w, fc1_w, wfrag);
  hipLaunchKernelGGL(fused_mlp, dim3(Btotal / ROWS_PER_BLOCK), dim3(256), 0, stream,
                     x, wfrag, fc1_b, fc2_w, fc2_b, outp);
}